// Round 5
// baseline (85.294 us; speedup 1.0000x reference)
//
#include <hip/hip_runtime.h>

// DCT2D, 8 threads per 8x8 block (one image row each), grid-stride unrolled x2
// for ILP (latency-bound at VGPR=16 / VALUBusy 24%).
//   t[v]    = sum_y (o[row][y]-128) * cs[y][v]          (local, row-major load)
//   -- lane transpose --  lane r now holds t[x][v=r], x=0..7
//   res[u]  = sum_x t[x] * cs[x][u]                      (local)
//   -- lane transpose --  lane r now holds out[r][v], v=0..7
//   coalesced 32B nontemporal store per lane (output never re-read; keep L3 for input).
// cs[a][b] = c[a][b]*alpha[b]*0.5, recovered exactly from inputs:
//   c[a][b]      = dct_tensor[a,0,b,0]   (c[0][0]==1)
//   alpha[b]*0.5 = scale[b,0] * 2*sqrt(2)
// cs is wave-uniform -> forced to SGPRs via readfirstlane.

typedef float vfloat4 __attribute__((ext_vector_type(4)));

__device__ __forceinline__ float uniformf(float v)
{
    return __int_as_float(__builtin_amdgcn_readfirstlane(__float_as_int(v)));
}

__device__ __forceinline__ void xpose8(float a[8], bool h1, bool h2, bool h4)
{
#pragma unroll
    for (int j = 0; j < 8; j += 2) {
        const int k = j + 1;
        float fj = __shfl_xor(a[k], 1);
        float fk = __shfl_xor(a[j], 1);
        float nj = h1 ? fj : a[j];
        float nk = h1 ? a[k] : fk;
        a[j] = nj; a[k] = nk;
    }
#pragma unroll
    for (int jj = 0; jj < 8; jj += 4) {
#pragma unroll
        for (int j0 = 0; j0 < 2; ++j0) {
            const int j = jj + j0, k = j + 2;
            float fj = __shfl_xor(a[k], 2);
            float fk = __shfl_xor(a[j], 2);
            float nj = h2 ? fj : a[j];
            float nk = h2 ? a[k] : fk;
            a[j] = nj; a[k] = nk;
        }
    }
#pragma unroll
    for (int j = 0; j < 4; ++j) {
        const int k = j + 4;
        float fj = __shfl_xor(a[k], 4);
        float fk = __shfl_xor(a[j], 4);
        float nj = h4 ? fj : a[j];
        float nk = h4 ? a[k] : fk;
        a[j] = nj; a[k] = nk;
    }
}

// full per-block pipeline on already-loaded row o[8] -> res[8] (output row `lane`)
__device__ __forceinline__ void dct_rows(const float o[8], float res[8],
                                         const float cs[8][8],
                                         bool h1, bool h2, bool h4)
{
    float t[8];
#pragma unroll
    for (int v = 0; v < 8; ++v) {
        float s = 0.0f;
#pragma unroll
        for (int y = 0; y < 8; ++y) s = fmaf(o[y], cs[y][v], s);
        t[v] = s;
    }
    xpose8(t, h1, h2, h4);
#pragma unroll
    for (int u = 0; u < 8; ++u) {
        float s = 0.0f;
#pragma unroll
        for (int xx = 0; xx < 8; ++xx) s = fmaf(t[xx], cs[xx][u], s);
        res[u] = s;
    }
    xpose8(res, h1, h2, h4);
}

__global__ __launch_bounds__(256) void dct2d_kernel(
    const float* __restrict__ x,
    const float* __restrict__ dct,     // [8,8,8,8] = c[x,u]*c[y,v]
    const float* __restrict__ scale,   // [8,8]
    float* __restrict__ out,
    int nblocks)
{
    const int tid  = blockIdx.x * blockDim.x + threadIdx.x;
    const int lane = tid & 7;
    const int nthreads = gridDim.x * blockDim.x;
    const int bstride  = nthreads >> 3;

    float cs[8][8];
#pragma unroll
    for (int b = 0; b < 8; ++b) {
        const float a05 = scale[b * 8] * 2.8284271247461903f;  // alpha[b]*0.5
#pragma unroll
        for (int a = 0; a < 8; ++a)
            cs[a][b] = uniformf(dct[a * 512 + b * 8] * a05);
    }

    const bool h1 = (lane & 1) != 0;
    const bool h2 = (lane & 2) != 0;
    const bool h4 = (lane & 4) != 0;

    int b = tid >> 3;
    // main: two independent blocks per iteration (ILP)
    for (; b + bstride < nblocks; b += 2 * bstride) {
        const float* rp0 = x + (size_t)b * 64 + lane * 8;
        const float* rp1 = x + (size_t)(b + bstride) * 64 + lane * 8;
        float4 a0 = *reinterpret_cast<const float4*>(rp0);
        float4 a1 = *reinterpret_cast<const float4*>(rp0 + 4);
        float4 b0 = *reinterpret_cast<const float4*>(rp1);
        float4 b1 = *reinterpret_cast<const float4*>(rp1 + 4);

        float o0[8] = {a0.x - 128.0f, a0.y - 128.0f, a0.z - 128.0f, a0.w - 128.0f,
                       a1.x - 128.0f, a1.y - 128.0f, a1.z - 128.0f, a1.w - 128.0f};
        float o1[8] = {b0.x - 128.0f, b0.y - 128.0f, b0.z - 128.0f, b0.w - 128.0f,
                       b1.x - 128.0f, b1.y - 128.0f, b1.z - 128.0f, b1.w - 128.0f};

        float r0[8], r1[8];
        dct_rows(o0, r0, cs, h1, h2, h4);
        dct_rows(o1, r1, cs, h1, h2, h4);

        float* op0 = out + (size_t)b * 64 + lane * 8;
        float* op1 = out + (size_t)(b + bstride) * 64 + lane * 8;
        vfloat4 s00 = { r0[0], r0[1], r0[2], r0[3] };
        vfloat4 s01 = { r0[4], r0[5], r0[6], r0[7] };
        vfloat4 s10 = { r1[0], r1[1], r1[2], r1[3] };
        vfloat4 s11 = { r1[4], r1[5], r1[6], r1[7] };
        __builtin_nontemporal_store(s00, reinterpret_cast<vfloat4*>(op0));
        __builtin_nontemporal_store(s01, reinterpret_cast<vfloat4*>(op0 + 4));
        __builtin_nontemporal_store(s10, reinterpret_cast<vfloat4*>(op1));
        __builtin_nontemporal_store(s11, reinterpret_cast<vfloat4*>(op1 + 4));
    }
    // tail: at most one block left
    if (b < nblocks) {
        const float* rp = x + (size_t)b * 64 + lane * 8;
        float4 q0 = *reinterpret_cast<const float4*>(rp);
        float4 q1 = *reinterpret_cast<const float4*>(rp + 4);
        float o[8] = {q0.x - 128.0f, q0.y - 128.0f, q0.z - 128.0f, q0.w - 128.0f,
                      q1.x - 128.0f, q1.y - 128.0f, q1.z - 128.0f, q1.w - 128.0f};
        float r[8];
        dct_rows(o, r, cs, h1, h2, h4);
        float* op = out + (size_t)b * 64 + lane * 8;
        vfloat4 s0 = { r[0], r[1], r[2], r[3] };
        vfloat4 s1 = { r[4], r[5], r[6], r[7] };
        __builtin_nontemporal_store(s0, reinterpret_cast<vfloat4*>(op));
        __builtin_nontemporal_store(s1, reinterpret_cast<vfloat4*>(op + 4));
    }
}

extern "C" void kernel_launch(void* const* d_in, const int* in_sizes, int n_in,
                              void* d_out, int out_size, void* d_ws, size_t ws_size,
                              hipStream_t stream)
{
    const float* x     = (const float*)d_in[0];
    const float* dct   = (const float*)d_in[1];
    const float* scale = (const float*)d_in[2];
    float* out = (float*)d_out;

    int nblocks = in_sizes[0] / 64;   // number of 8x8 tiles (262144*3)
    int block = 256;
    int grid  = 2048;                 // exactly fills 256 CU x 32 waves

    dct2d_kernel<<<grid, block, 0, stream>>>(x, dct, scale, out, nblocks);
}

// Round 6
// 79.158 us; speedup vs baseline: 1.0775x; 1.0775x over previous
//
#include <hip/hip_runtime.h>

// DCT2D, 8 threads per 8x8 block. Column-load variant: ONE lane-transpose
// instead of two (shuffle/DS pipe was co-bottleneck with memory).
//   lane r loads column r:  o[x] = X[b][x][r]          (8 x b32, L1 absorbs)
//   pass1 (local):  t[u]   = sum_x cs[x][u] * (o[x]-128)     -> T[u][col r]
//   -- one lane transpose --  lane r now holds T[r][y], y=0..7
//   pass2 (local):  res[v] = sum_y T[r][y] * cs[y][v]        -> out row r
//   coalesced 32B nontemporal row store (partial-line writes proven 2x cost).
// cs[a][b] = c[a][b]*alpha[b]*0.5, recovered exactly from inputs:
//   c[a][b]      = dct_tensor[a,0,b,0]   (c[0][0]==1)
//   alpha[b]*0.5 = scale[b,0] * 2*sqrt(2)
// cs wave-uniform -> SGPRs via readfirstlane.

typedef float vfloat4 __attribute__((ext_vector_type(4)));

__device__ __forceinline__ float uniformf(float v)
{
    return __int_as_float(__builtin_amdgcn_readfirstlane(__float_as_int(v)));
}

__device__ __forceinline__ void xpose8(float a[8], bool h1, bool h2, bool h4)
{
#pragma unroll
    for (int j = 0; j < 8; j += 2) {
        const int k = j + 1;
        float fj = __shfl_xor(a[k], 1);
        float fk = __shfl_xor(a[j], 1);
        float nj = h1 ? fj : a[j];
        float nk = h1 ? a[k] : fk;
        a[j] = nj; a[k] = nk;
    }
#pragma unroll
    for (int jj = 0; jj < 8; jj += 4) {
#pragma unroll
        for (int j0 = 0; j0 < 2; ++j0) {
            const int j = jj + j0, k = j + 2;
            float fj = __shfl_xor(a[k], 2);
            float fk = __shfl_xor(a[j], 2);
            float nj = h2 ? fj : a[j];
            float nk = h2 ? a[k] : fk;
            a[j] = nj; a[k] = nk;
        }
    }
#pragma unroll
    for (int j = 0; j < 4; ++j) {
        const int k = j + 4;
        float fj = __shfl_xor(a[k], 4);
        float fk = __shfl_xor(a[j], 4);
        float nj = h4 ? fj : a[j];
        float nk = h4 ? a[k] : fk;
        a[j] = nj; a[k] = nk;
    }
}

__global__ __launch_bounds__(256) void dct2d_kernel(
    const float* __restrict__ x,
    const float* __restrict__ dct,     // [8,8,8,8] = c[x,u]*c[y,v]
    const float* __restrict__ scale,   // [8,8]
    float* __restrict__ out,
    int nblocks)
{
    const int tid  = blockIdx.x * blockDim.x + threadIdx.x;
    const int lane = tid & 7;                    // which COLUMN of the 8x8 block
    const int nthreads = gridDim.x * blockDim.x;
    const int bstride  = nthreads >> 3;

    // wave-uniform folded constant matrix, forced to SGPRs
    float cs[8][8];
#pragma unroll
    for (int b = 0; b < 8; ++b) {
        const float a05 = scale[b * 8] * 2.8284271247461903f;  // alpha[b]*0.5
#pragma unroll
        for (int a = 0; a < 8; ++a)
            cs[a][b] = uniformf(dct[a * 512 + b * 8] * a05);   // c[a][b]*a05
    }

    const bool h1 = (lane & 1) != 0;
    const bool h2 = (lane & 2) != 0;
    const bool h4 = (lane & 4) != 0;

    for (int b = (tid >> 3); b < nblocks; b += bstride) {
        // column load: lane r reads X[b][x][r], x=0..7 (one base + imm offsets)
        const float* cp = x + (size_t)b * 64 + lane;
        float o[8];
#pragma unroll
        for (int xx = 0; xx < 8; ++xx) o[xx] = cp[xx * 8] - 128.0f;

        // pass 1 (local, sum over x): t[u] = T[u][col=lane]
        float t[8];
#pragma unroll
        for (int u = 0; u < 8; ++u) {
            float s = 0.0f;
#pragma unroll
            for (int xx = 0; xx < 8; ++xx) s = fmaf(o[xx], cs[xx][u], s);
            t[u] = s;
        }

        // single transpose: lane r now holds T[r][y], y=0..7
        xpose8(t, h1, h2, h4);

        // pass 2 (local, sum over y): res[v] = out[row=lane][v]
        float res[8];
#pragma unroll
        for (int v = 0; v < 8; ++v) {
            float s = 0.0f;
#pragma unroll
            for (int y = 0; y < 8; ++y) s = fmaf(t[y], cs[y][v], s);
            res[v] = s;
        }

        // coalesced nontemporal row store
        float* op = out + (size_t)b * 64 + lane * 8;
        vfloat4 s0 = { res[0], res[1], res[2], res[3] };
        vfloat4 s1 = { res[4], res[5], res[6], res[7] };
        __builtin_nontemporal_store(s0, reinterpret_cast<vfloat4*>(op));
        __builtin_nontemporal_store(s1, reinterpret_cast<vfloat4*>(op + 4));
    }
}

extern "C" void kernel_launch(void* const* d_in, const int* in_sizes, int n_in,
                              void* d_out, int out_size, void* d_ws, size_t ws_size,
                              hipStream_t stream)
{
    const float* x     = (const float*)d_in[0];
    const float* dct   = (const float*)d_in[1];
    const float* scale = (const float*)d_in[2];
    float* out = (float*)d_out;

    int nblocks = in_sizes[0] / 64;   // number of 8x8 tiles (262144*3)
    int block = 256;
    int grid  = 2048;                 // grid-stride; fills 256 CU x 8 WG

    dct2d_kernel<<<grid, block, 0, stream>>>(x, dct, scale, out, nblocks);
}

// Round 7
// 76.729 us; speedup vs baseline: 1.1116x; 1.0317x over previous
//
#include <hip/hip_runtime.h>

// DCT2D, 8 threads per 8x8 block, single lane-transpose, 2 CONSECUTIVE blocks
// per 8-lane group per iteration (wave covers 4 KB contiguous read + 4 KB
// contiguous write bursts; 16 hoisted loads -> 2x memory-level parallelism).
//   lane r loads column r:  o[x] = X[b][x][r]
//   pass1 (local):  t[u]   = sum_x cs[x][u] * (o[x]-128)
//   -- one lane transpose --  lane r now holds T[r][y]
//   pass2 (local):  res[v] = sum_y T[r][y] * cs[y][v]   -> out row r
//   coalesced 32B nontemporal row stores (keep L3 for input; FETCH=98MB<201MB).
// cs[a][b] = c[a][b]*alpha[b]*0.5, recovered exactly from inputs:
//   c[a][b]      = dct_tensor[a,0,b,0]   (c[0][0]==1)
//   alpha[b]*0.5 = scale[b,0] * 2*sqrt(2)

typedef float vfloat4 __attribute__((ext_vector_type(4)));

__device__ __forceinline__ float uniformf(float v)
{
    return __int_as_float(__builtin_amdgcn_readfirstlane(__float_as_int(v)));
}

__device__ __forceinline__ void xpose8(float a[8], bool h1, bool h2, bool h4)
{
#pragma unroll
    for (int j = 0; j < 8; j += 2) {
        const int k = j + 1;
        float fj = __shfl_xor(a[k], 1);
        float fk = __shfl_xor(a[j], 1);
        float nj = h1 ? fj : a[j];
        float nk = h1 ? a[k] : fk;
        a[j] = nj; a[k] = nk;
    }
#pragma unroll
    for (int jj = 0; jj < 8; jj += 4) {
#pragma unroll
        for (int j0 = 0; j0 < 2; ++j0) {
            const int j = jj + j0, k = j + 2;
            float fj = __shfl_xor(a[k], 2);
            float fk = __shfl_xor(a[j], 2);
            float nj = h2 ? fj : a[j];
            float nk = h2 ? a[k] : fk;
            a[j] = nj; a[k] = nk;
        }
    }
#pragma unroll
    for (int j = 0; j < 4; ++j) {
        const int k = j + 4;
        float fj = __shfl_xor(a[k], 4);
        float fk = __shfl_xor(a[j], 4);
        float nj = h4 ? fj : a[j];
        float nk = h4 ? a[k] : fk;
        a[j] = nj; a[k] = nk;
    }
}

// column data o[8] (already -128'd) -> output row `lane` res[8]
__device__ __forceinline__ void dct_block(const float o[8], float res[8],
                                          const float cs[8][8],
                                          bool h1, bool h2, bool h4)
{
    float t[8];
#pragma unroll
    for (int u = 0; u < 8; ++u) {
        float s = 0.0f;
#pragma unroll
        for (int xx = 0; xx < 8; ++xx) s = fmaf(o[xx], cs[xx][u], s);
        t[u] = s;
    }
    xpose8(t, h1, h2, h4);
#pragma unroll
    for (int v = 0; v < 8; ++v) {
        float s = 0.0f;
#pragma unroll
        for (int y = 0; y < 8; ++y) s = fmaf(t[y], cs[y][v], s);
        res[v] = s;
    }
}

__global__ __launch_bounds__(256) void dct2d_kernel(
    const float* __restrict__ x,
    const float* __restrict__ dct,     // [8,8,8,8] = c[x,u]*c[y,v]
    const float* __restrict__ scale,   // [8,8]
    float* __restrict__ out,
    int nblocks)
{
    const int tid  = blockIdx.x * blockDim.x + threadIdx.x;
    const int lane = tid & 7;                    // column index within 8x8 block
    const int g    = tid >> 3;                   // 8-lane group id
    const int ngroups = (gridDim.x * blockDim.x) >> 3;

    // wave-uniform folded constant matrix, forced to SGPRs
    float cs[8][8];
#pragma unroll
    for (int b = 0; b < 8; ++b) {
        const float a05 = scale[b * 8] * 2.8284271247461903f;  // alpha[b]*0.5
#pragma unroll
        for (int a = 0; a < 8; ++a)
            cs[a][b] = uniformf(dct[a * 512 + b * 8] * a05);   // c[a][b]*a05
    }

    const bool h1 = (lane & 1) != 0;
    const bool h2 = (lane & 2) != 0;
    const bool h4 = (lane & 4) != 0;

    int b0 = 2 * g;
    for (; b0 + 1 < nblocks; b0 += 2 * ngroups) {
        const float* p = x + (size_t)b0 * 64 + lane;
        // hoist all 16 column loads (2 consecutive blocks) before any compute
        float oA[8], oB[8];
#pragma unroll
        for (int xx = 0; xx < 8; ++xx) oA[xx] = p[xx * 8];
#pragma unroll
        for (int xx = 0; xx < 8; ++xx) oB[xx] = p[64 + xx * 8];
#pragma unroll
        for (int xx = 0; xx < 8; ++xx) { oA[xx] -= 128.0f; oB[xx] -= 128.0f; }

        float rA[8], rB[8];
        dct_block(oA, rA, cs, h1, h2, h4);
        dct_block(oB, rB, cs, h1, h2, h4);

        float* op = out + (size_t)b0 * 64 + lane * 8;
        vfloat4 sA0 = { rA[0], rA[1], rA[2], rA[3] };
        vfloat4 sA1 = { rA[4], rA[5], rA[6], rA[7] };
        vfloat4 sB0 = { rB[0], rB[1], rB[2], rB[3] };
        vfloat4 sB1 = { rB[4], rB[5], rB[6], rB[7] };
        __builtin_nontemporal_store(sA0, reinterpret_cast<vfloat4*>(op));
        __builtin_nontemporal_store(sA1, reinterpret_cast<vfloat4*>(op + 4));
        __builtin_nontemporal_store(sB0, reinterpret_cast<vfloat4*>(op + 64));
        __builtin_nontemporal_store(sB1, reinterpret_cast<vfloat4*>(op + 68));
    }
    // tail: at most one block left (not hit with 786432 blocks / 131072 per sweep)
    if (b0 < nblocks) {
        const float* p = x + (size_t)b0 * 64 + lane;
        float o[8];
#pragma unroll
        for (int xx = 0; xx < 8; ++xx) o[xx] = p[xx * 8] - 128.0f;
        float r[8];
        dct_block(o, r, cs, h1, h2, h4);
        float* op = out + (size_t)b0 * 64 + lane * 8;
        vfloat4 s0 = { r[0], r[1], r[2], r[3] };
        vfloat4 s1 = { r[4], r[5], r[6], r[7] };
        __builtin_nontemporal_store(s0, reinterpret_cast<vfloat4*>(op));
        __builtin_nontemporal_store(s1, reinterpret_cast<vfloat4*>(op + 4));
    }
}

extern "C" void kernel_launch(void* const* d_in, const int* in_sizes, int n_in,
                              void* d_out, int out_size, void* d_ws, size_t ws_size,
                              hipStream_t stream)
{
    const float* x     = (const float*)d_in[0];
    const float* dct   = (const float*)d_in[1];
    const float* scale = (const float*)d_in[2];
    float* out = (float*)d_out;

    int nblocks = in_sizes[0] / 64;   // number of 8x8 tiles (262144*3)
    int block = 256;
    int grid  = 2048;                 // 65536 groups; 786432/(2*65536)=6 iters exact

    dct2d_kernel<<<grid, block, 0, stream>>>(x, dct, scale, out, nblocks);
}